// Round 23
// baseline (313.751 us; speedup 1.0000x reference)
//
#include <hip/hip_runtime.h>
#include <cstddef>
#include <cstdint>

#define B_ 8
#define N_ 4096
#define C_ 512
#define H_ 8
#define HD_ 64
#define BH_ 64

typedef short  bf16x8 __attribute__((ext_vector_type(8)));
typedef float  f32x4  __attribute__((ext_vector_type(4)));
typedef ushort u16x8  __attribute__((ext_vector_type(8)));
typedef ushort u16x4  __attribute__((ext_vector_type(4)));

__device__ __forceinline__ float softplusf(float p) {
  return (p > 20.f) ? p : log1pf(expf(p));
}

__device__ __forceinline__ ushort f2bf(float f) {
  union { float f; unsigned u; } c; c.f = f;
  const unsigned r = c.u + 0x7fffu + ((c.u >> 16) & 1u);
  return (ushort)(r >> 16);
}
__device__ __forceinline__ float bf2f(ushort h) {
  union { unsigned u; float f; } c; c.u = ((unsigned)h) << 16;
  return c.f;
}

#define GLOAD16(g, l)                                                        \
  __builtin_amdgcn_global_load_lds(                                          \
      (const __attribute__((address_space(1))) void*)(g),                    \
      (__attribute__((address_space(3))) void*)(l), 16, 0, 0)

// ---------------- sinv[c] = 1/softplus(sp[c]) ----------------
__global__ void scale_kernel(const float* __restrict__ sp, float* __restrict__ sinv)
{
  const int c = threadIdx.x;
  sinv[c] = 1.f / softplusf(sp[c]);
}

// ---------------- fp32 -> bf16 (hi only, RNE) ----------------
__global__ __launch_bounds__(256) void cvt_hi(const float* __restrict__ in,
                                              ushort* __restrict__ hi)
{
  const size_t i = (size_t)blockIdx.x * 256 + threadIdx.x;
  const float4 a = ((const float4*)in)[i * 2];
  const float4 b = ((const float4*)in)[i * 2 + 1];
  const float f[8] = {a.x, a.y, a.z, a.w, b.x, b.y, b.z, b.w};
  u16x8 h;
  #pragma unroll
  for (int j = 0; j < 8; ++j) h[j] = f2bf(f[j]);
  *(u16x8*)&hi[i * 8] = h;
}

// ---------------- fp32 KxN weight -> bf16 (RNE), transposed to NxK (row stride 512) ----------------
__global__ __launch_bounds__(256) void cvt_w_t(const float* __restrict__ in,
                                               ushort* __restrict__ hi, int Nn)
{
  const int t  = blockIdx.x * 256 + threadIdx.x;
  const int n  = t >> 6;
  const int k8 = (t & 63) * 8;
  u16x8 h;
  #pragma unroll
  for (int j = 0; j < 8; ++j) h[j] = f2bf(in[(size_t)(k8 + j) * Nn + n]);
  *(u16x8*)&hi[(size_t)n * 512 + k8] = h;
}

// ---------------- bf16 MFMA GEMM: 256x256 tile, BK=32, 8 waves, 3-buf counted-vmcnt ----------------
// R22 diagnosis: 2-phase at 256^2 runs 1 block/CU -> NO cross-block overlap; the
// per-step vmcnt(0) drain exposes full HBM latency x16 steps (MfmaUtil 22%).
// This kernel = R19 geometry (BK=32 chunk-major, 0 bank conflicts measured) +
// R16 sync scheme (proven race-free): per step vmcnt(4) -> s_barrier ->
// STAGE(kt+2 -> buf[(t+2)%3]) -> COMPUTE(buf[t%3]). Loads stay 2 steps (~2000cy)
// ahead of use; never drains below 4 in-loop. WAR-safe: stage-after-barrier
// targets the buffer freed by compute(t-1). Ascending-k order -> bitwise-identical.
__global__ __launch_bounds__(512, 2) void gemm_bf16(
    const ushort* __restrict__ Ah, const ushort* __restrict__ Bh,
    const float* __restrict__ bias,
    ushort* __restrict__ ob0, ushort* __restrict__ ob1, ushort* __restrict__ ob2,
    float* __restrict__ outf,
    int ncolb, int s1, int s2, int r0, int r1, int r2)
{
  __shared__ ushort lds[3][16384];  // per buf: A[8192] B[8192] ushorts (32KB); 96KB total
  const int tid = threadIdx.x;
  const int bid = blockIdx.x;
  const int loc = bid >> 3;
  const int xcd = bid & 7;
  const int row0 = ((xcd << 4) + loc / ncolb) * 256;  // 128 row-blocks, 16 per XCD
  const int col0 = (loc % ncolb) * 256;

  const int lane = tid & 63;
  const int li   = lane & 15;
  const int kq   = lane >> 4;
  const int w    = tid >> 6;          // wave 0..7
  const int wr   = (w >> 2) * 128;    // 2 M-groups
  const int wc   = (w & 3) * 64;      // 4 N-groups
  const int wbase = tid & 448;        // wave-uniform thread base

  f32x4 acc[8][4] = {};

  auto STAGE = [&](int buf, int t) {
    ushort* l = &lds[buf][0];
    const int k0 = t * 32;
    #pragma unroll
    for (int it = 0; it < 2; ++it) {
      const int c   = it * 512 + tid;       // A chunk 0..1023
      const int cw  = it * 512 + wbase;
      const int kb  = c >> 8;               // 0..3 (8 k each)
      const int row = c & 255;
      GLOAD16(Ah + (size_t)(row0 + row) * 512 + k0 + kb * 8, &l[cw * 8]);
    }
    #pragma unroll
    for (int it = 0; it < 2; ++it) {
      const int c   = it * 512 + tid;       // B chunk 0..1023
      const int cw  = it * 512 + wbase;
      const int kb  = c >> 8;
      const int col = c & 255;
      GLOAD16(Bh + (size_t)(col0 + col) * 512 + k0 + kb * 8, &l[8192 + cw * 8]);
    }
  };

  auto COMPUTE = [&](int buf) {
    const ushort* l = &lds[buf][0];
    bf16x8 bv[4];
    #pragma unroll
    for (int n = 0; n < 4; ++n)
      bv[n] = *(const bf16x8*)&l[8192 + (kq * 256 + wc + n * 16 + li) * 8];
    __builtin_amdgcn_s_setprio(1);
    #pragma unroll
    for (int m = 0; m < 8; ++m) {
      const bf16x8 av = *(const bf16x8*)&l[(kq * 256 + wr + m * 16 + li) * 8];
      #pragma unroll
      for (int n = 0; n < 4; ++n)
        acc[m][n] = __builtin_amdgcn_mfma_f32_16x16x32_bf16(av, bv[n], acc[m][n], 0, 0, 0);
    }
    __builtin_amdgcn_s_setprio(0);
  };

  auto STEP = [&](int t, int buf) {
    asm volatile("s_waitcnt vmcnt(4)" ::: "memory");
    __builtin_amdgcn_s_barrier();
    __builtin_amdgcn_sched_barrier(0);
    if (t < 14) STAGE((buf + 2 >= 3) ? buf + 2 - 3 : buf + 2, t + 2);
    COMPUTE(buf);
    __builtin_amdgcn_sched_barrier(0);
  };

  // prologue: K-tiles 0,1 in flight (8 loads/thread)
  STAGE(0, 0);
  STAGE(1, 1);
  // 15 pipelined steps (5 groups of 3, fixed buffer ids)
  #pragma unroll 1
  for (int g = 0; g < 5; ++g) {
    STEP(3 * g + 0, 0);
    STEP(3 * g + 1, 1);
    STEP(3 * g + 2, 2);
  }
  // tail t=15 (buf 0): only tile 15's loads may remain
  asm volatile("s_waitcnt vmcnt(0)" ::: "memory");
  __builtin_amdgcn_s_barrier();
  __builtin_amdgcn_sched_barrier(0);
  COMPUTE(0);

  // epilogue: C/D map col=lane&15, row=(lane>>4)*4+reg
  if (outf) {
    #pragma unroll
    for (int m = 0; m < 8; ++m)
      #pragma unroll
      for (int n = 0; n < 4; ++n) {
        const int col = col0 + wc + n * 16 + li;
        const int row = row0 + wr + m * 16 + kq * 4;
        const float bv = bias[col];
        #pragma unroll
        for (int r = 0; r < 4; ++r)
          outf[(size_t)(row + r) * 512 + col] = acc[m][n][r] + bv;
      }
  } else {
    ushort* dest; int cbase, relu;
    if (col0 < s1)      { dest = ob0; cbase = 0;  relu = r0; }
    else if (col0 < s2) { dest = ob1; cbase = s1; relu = r1; }
    else                { dest = ob2; cbase = s2; relu = r2; }
    #pragma unroll
    for (int m = 0; m < 8; ++m)
      #pragma unroll
      for (int n = 0; n < 4; ++n) {
        const int col = col0 + wc + n * 16 + li;
        const int row = row0 + wr + m * 16 + kq * 4;
        #pragma unroll
        for (int r = 0; r < 4; ++r) {
          float v = acc[m][n][r];
          if (relu) v = fmaxf(v, 0.f) + 1e-6f;
          dest[(size_t)(row + r) * 512 + (col - cbase)] = f2bf(v);
        }
      }
  }
}

// ---------------- focus on bf16 q and k in one launch ----------------
__global__ __launch_bounds__(256) void focus2(ushort* __restrict__ qb, ushort* __restrict__ kb,
                                              const float* __restrict__ sinv)
{
  const int rid  = blockIdx.x * 4 + (threadIdx.x >> 6);
  const int lane = threadIdx.x & 63;
  ushort* t = (rid < B_ * N_) ? qb : kb;
  const int row = rid & (B_ * N_ - 1);
  ushort* p = t + (size_t)row * 512 + lane * 8;
  const u16x8 raw = *(const u16x8*)p;
  const float4 sa = *(const float4*)&sinv[lane * 8];
  const float4 sb = *(const float4*)&sinv[lane * 8 + 4];
  const float sc[8] = {sa.x, sa.y, sa.z, sa.w, sb.x, sb.y, sb.z, sb.w};
  float tv[8];
  float s2 = 0.f, s6 = 0.f;
  #pragma unroll
  for (int i = 0; i < 8; ++i) {
    const float x = bf2f(raw[i]) * sc[i];
    tv[i] = x;
    const float x3 = x * x * x;
    s2 = fmaf(x, x, s2);
    s6 = fmaf(x3, x3, s6);
  }
  #pragma unroll
  for (int off = 32; off > 0; off >>= 1) {
    s2 += __shfl_xor(s2, off);
    s6 += __shfl_xor(s6, off);
  }
  const float f = sqrtf(s2 / s6);
  u16x8 o;
  #pragma unroll
  for (int i = 0; i < 8; ++i) o[i] = f2bf(tv[i] * tv[i] * tv[i] * f);
  *(u16x8*)p = o;
}

// ---------------- kvm via MFMA: kvmT[bh][d][c] = sum_n v[n][d]*k[n][c] ; fused ksum ----------------
__global__ __launch_bounds__(256, 2) void kvm_kernel(
    const ushort* __restrict__ kf, const ushort* __restrict__ vf,
    float* __restrict__ kvmT, float* __restrict__ ksum)
{
  __shared__ ushort KT[2048];  // [c=64][32] ushort, chunk-swizzled (4KB)
  __shared__ ushort VT[2048];
  const int bh = blockIdx.x, bb = bh >> 3, h = bh & 7;
  const int n0 = blockIdx.y * 512;
  const int tid = threadIdx.x;
  const int lane = tid & 63;
  const int li   = lane & 15;
  const int kq   = lane >> 4;
  const int w    = tid >> 6;      // wave -> c-row group w*16
  const int r    = tid >> 3;      // staging: n within tile (0..31)
  const int cg   = (tid & 7) * 8; // staging: c base

  f32x4 acc[4] = {};
  float ks[8] = {};

  u16x8 kraw = *(const u16x8*)&kf[((size_t)(bb * N_ + n0 + r)) * 512 + h * 64 + cg];
  u16x8 vraw = *(const u16x8*)&vf[((size_t)(bb * N_ + n0 + r)) * 512 + h * 64 + cg];

  #pragma unroll 1
  for (int t = 0; t < 16; ++t) {
    u16x8 knext = kraw, vnext = vraw;
    if (t < 15) {
      const size_t gn = ((size_t)(bb * N_ + n0 + (t + 1) * 32 + r)) * 512 + h * 64 + cg;
      knext = *(const u16x8*)&kf[gn];
      vnext = *(const u16x8*)&vf[gn];
    }
    #pragma unroll
    for (int j = 0; j < 8; ++j) {
      const int c = cg + j;
      const int p = (r >> 3) ^ ((c ^ (c >> 3)) & 3);
      const int idx = c * 32 + p * 8 + (r & 7);
      KT[idx] = kraw[j];
      VT[idx] = vraw[j];
      ks[j] += bf2f(kraw[j]);
    }
    __syncthreads();
    {
      const int ca = w * 16 + li;
      const bf16x8 av = *(const bf16x8*)&KT[ca * 32 + ((kq ^ ((ca ^ (ca >> 3)) & 3)) * 8)];
      #pragma unroll
      for (int dt = 0; dt < 4; ++dt) {
        const int cb = dt * 16 + li;
        const bf16x8 bv = *(const bf16x8*)&VT[cb * 32 + ((kq ^ ((cb ^ (cb >> 3)) & 3)) * 8)];
        acc[dt] = __builtin_amdgcn_mfma_f32_16x16x32_bf16(av, bv, acc[dt], 0, 0, 0);
      }
    }
    __syncthreads();
    kraw = knext;
    vraw = vnext;
  }

  #pragma unroll
  for (int dt = 0; dt < 4; ++dt)
    #pragma unroll
    for (int rr = 0; rr < 4; ++rr)
      atomicAdd(&kvmT[(size_t)(bh * 64 + dt * 16 + li) * 64 + w * 16 + kq * 4 + rr],
                acc[dt][rr]);
  #pragma unroll
  for (int j = 0; j < 8; ++j) {
    float s = ks[j];
    s += __shfl_xor(s, 8);
    s += __shfl_xor(s, 16);
    s += __shfl_xor(s, 32);
    if ((lane & 56) == 0) atomicAdd(&ksum[bh * 64 + cg + j], s);
  }
}

// ---------------- attnout via MFMA: out[n][d] = z(n) * sum_c q[n][c]*kvm[c][d] ----------------
__global__ __launch_bounds__(256, 3) void attnout_kernel(
    const ushort* __restrict__ qf, const float* __restrict__ kvmT,
    const float* __restrict__ ksum, ushort* __restrict__ out)
{
  __shared__ ushort As[8 * 256 * 8];  // [kb][row][8] bf16 = 32KB
  __shared__ ushort Bs[8 * 64 * 8];   // [kb][d][8] bf16 = 8KB
  __shared__ float zrow[256];
  __shared__ float ksl[64];
  const int bh = blockIdx.x, bb = bh >> 3, h = bh & 7;
  const int n0 = blockIdx.y * 256;
  const int tid = threadIdx.x;
  const int lane = tid & 63;
  const int li   = lane & 15;
  const int kq   = lane >> 4;
  const int wv   = tid >> 6;
  const int w64  = tid & 192;

  #pragma unroll
  for (int it = 0; it < 8; ++it) {
    const int c   = it * 256 + tid;
    const int cw  = it * 256 + w64;
    const int kb  = c >> 8;
    const int row = c & 255;
    GLOAD16(qf + ((size_t)(bb * N_ + n0 + row)) * 512 + h * 64 + kb * 8,
            &As[cw * 8]);
  }
  {
    const int d  = tid >> 2;
    const int cg = (tid & 3) * 16;
    const float* src = &kvmT[(size_t)(bh * 64 + d) * 64 + cg];
    const float4 f0 = *(const float4*)&src[0];
    const float4 f1 = *(const float4*)&src[4];
    const float4 f2 = *(const float4*)&src[8];
    const float4 f3 = *(const float4*)&src[12];
    u16x8 b0, b1;
    b0[0]=f2bf(f0.x); b0[1]=f2bf(f0.y); b0[2]=f2bf(f0.z); b0[3]=f2bf(f0.w);
    b0[4]=f2bf(f1.x); b0[5]=f2bf(f1.y); b0[6]=f2bf(f1.z); b0[7]=f2bf(f1.w);
    b1[0]=f2bf(f2.x); b1[1]=f2bf(f2.y); b1[2]=f2bf(f2.z); b1[3]=f2bf(f2.w);
    b1[4]=f2bf(f3.x); b1[5]=f2bf(f3.y); b1[6]=f2bf(f3.z); b1[7]=f2bf(f3.w);
    *(u16x8*)&Bs[(((cg >> 3)    ) * 64 + d) * 8] = b0;
    *(u16x8*)&Bs[(((cg >> 3) + 1) * 64 + d) * 8] = b1;
  }
  if (tid < 64) ksl[tid] = ksum[bh * 64 + tid];
  __syncthreads();

  {
    float p = 0.f;
    #pragma unroll
    for (int kb = 0; kb < 8; ++kb) {
      const u16x8 qv = *(const u16x8*)&As[(kb * 256 + tid) * 8];
      #pragma unroll
      for (int j = 0; j < 8; ++j) p = fmaf(bf2f(qv[j]), ksl[kb * 8 + j], p);
    }
    zrow[tid] = 1.f / (p + 1e-6f);
  }

  f32x4 acc2[4][4] = {};
  #pragma unroll
  for (int kh = 0; kh < 2; ++kh) {
    bf16x8 bv[4];
    #pragma unroll
    for (int dt = 0; dt < 4; ++dt)
      bv[dt] = *(const bf16x8*)&Bs[((kh * 4 + kq) * 64 + dt * 16 + li) * 8];
    #pragma unroll
    for (int mt = 0; mt < 4; ++mt) {
      const bf16x8 av = *(const bf16x8*)&As[((kh * 4 + kq) * 256 + wv * 64 + mt * 16 + li) * 8];
      #pragma unroll
      for (int dt = 0; dt < 4; ++dt)
        acc2[mt][dt] = __builtin_amdgcn_mfma_f32_16x16x32_bf16(av, bv[dt], acc2[mt][dt], 0, 0, 0);
    }
  }
  __syncthreads();

  #pragma unroll
  for (int mt = 0; mt < 4; ++mt) {
    const float4 zv = *(const float4*)&zrow[wv * 64 + mt * 16 + kq * 4];
    const float za[4] = {zv.x, zv.y, zv.z, zv.w};
    const int rowb = n0 + wv * 64 + mt * 16 + kq * 4;
    #pragma unroll
    for (int dt = 0; dt < 4; ++dt) {
      const int col = h * 64 + dt * 16 + li;
      #pragma unroll
      for (int r = 0; r < 4; ++r)
        out[((size_t)(bb * N_ + rowb + r)) * 512 + col] = f2bf(acc2[mt][dt][r] * za[r]);
    }
  }
}

// ---------------- depthwise 5x5 conv (bf16 in/out), register-rolling; += ano; emits proj input ----------------
__global__ __launch_bounds__(256) void dwconv_hi(
    const ushort* __restrict__ qf, const float* __restrict__ w,
    const float* __restrict__ wb, const ushort* __restrict__ ano,
    ushort* __restrict__ oh)
{
  __shared__ float ws_[64 * 25];
  const int tid = threadIdx.x;
  for (int i = tid; i < 64 * 25; i += 256) ws_[i] = w[i];
  __syncthreads();

  const int bh = blockIdx.x, bb = bh >> 3, h = bh & 7;
  const int hd = tid & 63;
  const int s  = blockIdx.y * 4 + (tid >> 6);
  const int x  = s & 63;
  const int y0 = (s >> 6) * 8;

  float wreg[25];
  #pragma unroll
  for (int i = 0; i < 25; ++i) wreg[i] = ws_[hd * 25 + i];

  float acc[8];
  const float bias = wb[hd];
  #pragma unroll
  for (int j = 0; j < 8; ++j) acc[j] = bias;

  const ushort* base = qf + (size_t)bb * N_ * 512 + h * 64 + hd;
  #pragma unroll
  for (int kx = 0; kx < 5; ++kx) {
    const int xx  = x + kx - 2;
    const bool xok = (unsigned)xx < 64u;
    const int xxc = min(max(xx, 0), 63);
    float col[12];
    #pragma unroll
    for (int r = 0; r < 12; ++r) {
      const int yy  = y0 + r - 2;
      const bool ok = xok && ((unsigned)yy < 64u);
      const int yyc = min(max(yy, 0), 63);
      const float v = bf2f(base[(size_t)(yyc * 64 + xxc) * 512]);
      col[r] = ok ? v : 0.f;
    }
    #pragma unroll
    for (int ky = 0; ky < 5; ++ky) {
      const float wv = wreg[ky * 5 + kx];
      #pragma unroll
      for (int j = 0; j < 8; ++j)
        acc[j] = fmaf(wv, col[j + ky], acc[j]);
    }
  }

  #pragma unroll
  for (int j = 0; j < 8; ++j) {
    const int p = (y0 + j) * 64 + x;
    const size_t idx = ((size_t)(bb * N_ + p)) * 512 + h * 64 + hd;
    oh[idx] = f2bf(bf2f(ano[idx]) + acc[j]);
  }
}

extern "C" void kernel_launch(void* const* d_in, const int* in_sizes, int n_in,
                              void* d_out, int out_size, void* d_ws, size_t ws_size,
                              hipStream_t stream) {
  (void)in_sizes; (void)n_in; (void)out_size; (void)ws_size;
  const float* x     = (const float*)d_in[0];
  const float* Wq    = (const float*)d_in[1];
  const float* Wkv   = (const float*)d_in[2];
  const float* Wp    = (const float*)d_in[3];
  const float* bp    = (const float*)d_in[4];
  const float* sp    = (const float*)d_in[5];
  const float* dwc_w = (const float*)d_in[6];
  const float* dwc_b = (const float*)d_in[7];
  float* out = (float*)d_out;

  char* ws = (char*)d_ws;
  ushort* xh   = (ushort*)ws;                        // 32MB: x hi; later proj-input (bf16)
  ushort* qbuf = (ushort*)(ws + 33554432ull);        // 32MB focused q (bf16)
  ushort* kbuf = (ushort*)(ws + 67108864ull);        // 32MB k (bf16); later ano (bf16)
  char*   w0   = ws + 100663296ull;
  ushort* Bqh  = (ushort*)w0;                        // 1536x512 bf16 (rows: Wq 0..511, Wkv 512..1535)
  ushort* Bph  = Bqh + 786432;                       // 512x512 bf16
  float*  kvmb = (float*)(Bph + 262144);             // 1MB (kvmT)
  float*  ksum = kvmb + 262144;                      // 16KB
  float*  sinv = ksum + 4096;                        // 2KB
  ushort* vbuf = (ushort*)d_out;                     // v (bf16, 32MB) aliases d_out
  ushort* ano  = kbuf;                               // attn-out aliases k

  const int M = B_ * N_;  // 32768

  scale_kernel<<<1, 512, 0, stream>>>(sp, sinv);
  cvt_hi<<<8192, 256, 0, stream>>>(x, xh);
  cvt_w_t<<<128, 256, 0, stream>>>(Wq, Bqh, 512);
  // Wkv occupies rows [512,1536): offset = 512 rows * 512 stride = 262144
  cvt_w_t<<<256, 256, 0, stream>>>(Wkv, Bqh + 262144, 1024);
  cvt_w_t<<<128, 256, 0, stream>>>(Wp, Bph, 512);
  // fused q|k|v GEMM (256^2 tiles): 128 row-blocks x 6 col-blocks = 768 blocks
  gemm_bf16<<<768, 512, 0, stream>>>(
      xh, Bqh, nullptr, qbuf, kbuf, vbuf, nullptr, 6, 512, 1024, 1, 1, 0);
  focus2<<<2 * M / 4, 256, 0, stream>>>(qbuf, kbuf, sinv);
  hipMemsetAsync(kvmb, 0, (262144 + 4096) * sizeof(float), stream);
  // kvm via MFMA: grid (bh, 8 n-splits of 512)
  kvm_kernel<<<dim3(BH_, 8), 256, 0, stream>>>(kbuf, vbuf, kvmb, ksum);
  attnout_kernel<<<dim3(BH_, N_ / 256), 256, 0, stream>>>(qbuf, kvmb, ksum, ano);
  dwconv_hi<<<dim3(BH_, 128), 256, 0, stream>>>(qbuf, dwc_w, dwc_b, ano, xh);
  // proj (256^2 tiles): 128 x 2 = 256 blocks; fp32 out + bias -> d_out
  gemm_bf16<<<256, 512, 0, stream>>>(
      xh, Bph, bp, nullptr, nullptr, nullptr, out, 2, 512, 512, 0, 0, 0);
}

// Round 24
// 286.176 us; speedup vs baseline: 1.0964x; 1.0964x over previous
//
#include <hip/hip_runtime.h>
#include <cstddef>
#include <cstdint>

#define B_ 8
#define N_ 4096
#define C_ 512
#define H_ 8
#define HD_ 64
#define BH_ 64

typedef short  bf16x8 __attribute__((ext_vector_type(8)));
typedef float  f32x4  __attribute__((ext_vector_type(4)));
typedef ushort u16x8  __attribute__((ext_vector_type(8)));
typedef ushort u16x4  __attribute__((ext_vector_type(4)));

__device__ __forceinline__ float softplusf(float p) {
  return (p > 20.f) ? p : log1pf(expf(p));
}

__device__ __forceinline__ ushort f2bf(float f) {
  union { float f; unsigned u; } c; c.f = f;
  const unsigned r = c.u + 0x7fffu + ((c.u >> 16) & 1u);
  return (ushort)(r >> 16);
}
__device__ __forceinline__ float bf2f(ushort h) {
  union { unsigned u; float f; } c; c.u = ((unsigned)h) << 16;
  return c.f;
}

#define GLOAD16(g, l)                                                        \
  __builtin_amdgcn_global_load_lds(                                          \
      (const __attribute__((address_space(1))) void*)(g),                    \
      (__attribute__((address_space(3))) void*)(l), 16, 0, 0)

// ---------------- sinv[c] = 1/softplus(sp[c]) ----------------
__global__ void scale_kernel(const float* __restrict__ sp, float* __restrict__ sinv)
{
  const int c = threadIdx.x;
  sinv[c] = 1.f / softplusf(sp[c]);
}

// ---------------- fp32 -> bf16 (hi only, RNE) ----------------
__global__ __launch_bounds__(256) void cvt_hi(const float* __restrict__ in,
                                              ushort* __restrict__ hi)
{
  const size_t i = (size_t)blockIdx.x * 256 + threadIdx.x;
  const float4 a = ((const float4*)in)[i * 2];
  const float4 b = ((const float4*)in)[i * 2 + 1];
  const float f[8] = {a.x, a.y, a.z, a.w, b.x, b.y, b.z, b.w};
  u16x8 h;
  #pragma unroll
  for (int j = 0; j < 8; ++j) h[j] = f2bf(f[j]);
  *(u16x8*)&hi[i * 8] = h;
}

// ---------------- fp32 KxN weight -> bf16 (RNE), transposed to NxK (row stride 512) ----------------
__global__ __launch_bounds__(256) void cvt_w_t(const float* __restrict__ in,
                                               ushort* __restrict__ hi, int Nn)
{
  const int t  = blockIdx.x * 256 + threadIdx.x;
  const int n  = t >> 6;
  const int k8 = (t & 63) * 8;
  u16x8 h;
  #pragma unroll
  for (int j = 0; j < 8; ++j) h[j] = f2bf(in[(size_t)(k8 + j) * Nn + n]);
  *(u16x8*)&hi[(size_t)n * 512 + k8] = h;
}

// ---------------- bf16 MFMA GEMM: 256x256 tile, BK=64, 8 waves, 2-phase dbuf ----------------
// FINAL configuration (best measured: R18 286.4us / R22 288.5us total; qkv 94us).
// Exhaustive ablation R11-R23: BK 32/64, single/double/triple buffer, counted
// vmcnt (2 schemes), 8/16 waves, 128^2/256^2 -- only 128^2 -> 256^2 moved perf.
// The 2-phase barrier drain is this family's structural floor.
__global__ __launch_bounds__(512, 2) void gemm_bf16(
    const ushort* __restrict__ Ah, const ushort* __restrict__ Bh,
    const float* __restrict__ bias,
    ushort* __restrict__ ob0, ushort* __restrict__ ob1, ushort* __restrict__ ob2,
    float* __restrict__ outf,
    int ncolb, int s1, int s2, int r0, int r1, int r2)
{
  __shared__ ushort lds[2][32768];  // per buf: A[16384] B[16384] ushorts
  const int tid = threadIdx.x;
  const int bid = blockIdx.x;
  const int loc = bid >> 3;
  const int xcd = bid & 7;
  const int row0 = ((xcd << 4) + loc / ncolb) * 256;  // 128 row-blocks, 16 per XCD
  const int col0 = (loc % ncolb) * 256;

  const int lane = tid & 63;
  const int li   = lane & 15;
  const int kq   = lane >> 4;
  const int w    = tid >> 6;          // wave 0..7
  const int wr   = (w >> 2) * 128;    // 2 M-groups
  const int wc   = (w & 3) * 64;      // 4 N-groups
  const int wbase = tid & 448;        // wave-uniform thread base

  f32x4 acc[8][4] = {};

  auto STAGE = [&](int buf, int t) {
    ushort* l = &lds[buf][0];
    const int k0 = t * 64;
    #pragma unroll
    for (int it = 0; it < 4; ++it) {
      const int c   = it * 512 + tid;       // A chunk 0..2047
      const int cw  = it * 512 + wbase;
      const int kb  = c >> 8;               // 0..7 (8 k each)
      const int row = c & 255;
      GLOAD16(Ah + (size_t)(row0 + row) * 512 + k0 + kb * 8, &l[cw * 8]);
    }
    #pragma unroll
    for (int it = 0; it < 4; ++it) {
      const int c   = it * 512 + tid;       // B chunk 0..2047
      const int cw  = it * 512 + wbase;
      const int kb  = c >> 8;
      const int col = c & 255;
      GLOAD16(Bh + (size_t)(col0 + col) * 512 + k0 + kb * 8, &l[16384 + cw * 8]);
    }
  };

  auto COMPUTE = [&](int buf) {
    const ushort* l = &lds[buf][0];
    #pragma unroll
    for (int kk = 0; kk < 2; ++kk) {
      const int kb = kk * 4 + kq;           // 0..7
      bf16x8 bv[4];
      #pragma unroll
      for (int n = 0; n < 4; ++n)
        bv[n] = *(const bf16x8*)&l[16384 + (kb * 256 + wc + n * 16 + li) * 8];
      __builtin_amdgcn_s_setprio(1);
      #pragma unroll
      for (int m = 0; m < 8; ++m) {
        const bf16x8 av = *(const bf16x8*)&l[(kb * 256 + wr + m * 16 + li) * 8];
        #pragma unroll
        for (int n = 0; n < 4; ++n)
          acc[m][n] = __builtin_amdgcn_mfma_f32_16x16x32_bf16(av, bv[n], acc[m][n], 0, 0, 0);
      }
      __builtin_amdgcn_s_setprio(0);
    }
  };

  // 8 K-steps of 64; dbuf prefetch-before-compute, one barrier per step
  STAGE(0, 0);
  __syncthreads();
  #pragma unroll 1
  for (int t = 0; t < 3; ++t) {
    STAGE(1, 2 * t + 1);
    COMPUTE(0);
    __syncthreads();
    STAGE(0, 2 * t + 2);
    COMPUTE(1);
    __syncthreads();
  }
  STAGE(1, 7);
  COMPUTE(0);
  __syncthreads();
  COMPUTE(1);

  // epilogue: C/D map col=lane&15, row=(lane>>4)*4+reg
  if (outf) {
    #pragma unroll
    for (int m = 0; m < 8; ++m)
      #pragma unroll
      for (int n = 0; n < 4; ++n) {
        const int col = col0 + wc + n * 16 + li;
        const int row = row0 + wr + m * 16 + kq * 4;
        const float bv = bias[col];
        #pragma unroll
        for (int r = 0; r < 4; ++r)
          outf[(size_t)(row + r) * 512 + col] = acc[m][n][r] + bv;
      }
  } else {
    ushort* dest; int cbase, relu;
    if (col0 < s1)      { dest = ob0; cbase = 0;  relu = r0; }
    else if (col0 < s2) { dest = ob1; cbase = s1; relu = r1; }
    else                { dest = ob2; cbase = s2; relu = r2; }
    #pragma unroll
    for (int m = 0; m < 8; ++m)
      #pragma unroll
      for (int n = 0; n < 4; ++n) {
        const int col = col0 + wc + n * 16 + li;
        const int row = row0 + wr + m * 16 + kq * 4;
        #pragma unroll
        for (int r = 0; r < 4; ++r) {
          float v = acc[m][n][r];
          if (relu) v = fmaxf(v, 0.f) + 1e-6f;
          dest[(size_t)(row + r) * 512 + (col - cbase)] = f2bf(v);
        }
      }
  }
}

// ---------------- focus on bf16 q and k in one launch ----------------
__global__ __launch_bounds__(256) void focus2(ushort* __restrict__ qb, ushort* __restrict__ kb,
                                              const float* __restrict__ sinv)
{
  const int rid  = blockIdx.x * 4 + (threadIdx.x >> 6);
  const int lane = threadIdx.x & 63;
  ushort* t = (rid < B_ * N_) ? qb : kb;
  const int row = rid & (B_ * N_ - 1);
  ushort* p = t + (size_t)row * 512 + lane * 8;
  const u16x8 raw = *(const u16x8*)p;
  const float4 sa = *(const float4*)&sinv[lane * 8];
  const float4 sb = *(const float4*)&sinv[lane * 8 + 4];
  const float sc[8] = {sa.x, sa.y, sa.z, sa.w, sb.x, sb.y, sb.z, sb.w};
  float tv[8];
  float s2 = 0.f, s6 = 0.f;
  #pragma unroll
  for (int i = 0; i < 8; ++i) {
    const float x = bf2f(raw[i]) * sc[i];
    tv[i] = x;
    const float x3 = x * x * x;
    s2 = fmaf(x, x, s2);
    s6 = fmaf(x3, x3, s6);
  }
  #pragma unroll
  for (int off = 32; off > 0; off >>= 1) {
    s2 += __shfl_xor(s2, off);
    s6 += __shfl_xor(s6, off);
  }
  const float f = sqrtf(s2 / s6);
  u16x8 o;
  #pragma unroll
  for (int i = 0; i < 8; ++i) o[i] = f2bf(tv[i] * tv[i] * tv[i] * f);
  *(u16x8*)p = o;
}

// ---------------- kvm via MFMA: kvmT[bh][d][c] = sum_n v[n][d]*k[n][c] ; fused ksum ----------------
__global__ __launch_bounds__(256, 2) void kvm_kernel(
    const ushort* __restrict__ kf, const ushort* __restrict__ vf,
    float* __restrict__ kvmT, float* __restrict__ ksum)
{
  __shared__ ushort KT[2048];  // [c=64][32] ushort, chunk-swizzled (4KB)
  __shared__ ushort VT[2048];
  const int bh = blockIdx.x, bb = bh >> 3, h = bh & 7;
  const int n0 = blockIdx.y * 512;
  const int tid = threadIdx.x;
  const int lane = tid & 63;
  const int li   = lane & 15;
  const int kq   = lane >> 4;
  const int w    = tid >> 6;      // wave -> c-row group w*16
  const int r    = tid >> 3;      // staging: n within tile (0..31)
  const int cg   = (tid & 7) * 8; // staging: c base

  f32x4 acc[4] = {};
  float ks[8] = {};

  u16x8 kraw = *(const u16x8*)&kf[((size_t)(bb * N_ + n0 + r)) * 512 + h * 64 + cg];
  u16x8 vraw = *(const u16x8*)&vf[((size_t)(bb * N_ + n0 + r)) * 512 + h * 64 + cg];

  #pragma unroll 1
  for (int t = 0; t < 16; ++t) {
    u16x8 knext = kraw, vnext = vraw;
    if (t < 15) {
      const size_t gn = ((size_t)(bb * N_ + n0 + (t + 1) * 32 + r)) * 512 + h * 64 + cg;
      knext = *(const u16x8*)&kf[gn];
      vnext = *(const u16x8*)&vf[gn];
    }
    #pragma unroll
    for (int j = 0; j < 8; ++j) {
      const int c = cg + j;
      const int p = (r >> 3) ^ ((c ^ (c >> 3)) & 3);
      const int idx = c * 32 + p * 8 + (r & 7);
      KT[idx] = kraw[j];
      VT[idx] = vraw[j];
      ks[j] += bf2f(kraw[j]);
    }
    __syncthreads();
    {
      const int ca = w * 16 + li;
      const bf16x8 av = *(const bf16x8*)&KT[ca * 32 + ((kq ^ ((ca ^ (ca >> 3)) & 3)) * 8)];
      #pragma unroll
      for (int dt = 0; dt < 4; ++dt) {
        const int cb = dt * 16 + li;
        const bf16x8 bv = *(const bf16x8*)&VT[cb * 32 + ((kq ^ ((cb ^ (cb >> 3)) & 3)) * 8)];
        acc[dt] = __builtin_amdgcn_mfma_f32_16x16x32_bf16(av, bv, acc[dt], 0, 0, 0);
      }
    }
    __syncthreads();
    kraw = knext;
    vraw = vnext;
  }

  #pragma unroll
  for (int dt = 0; dt < 4; ++dt)
    #pragma unroll
    for (int rr = 0; rr < 4; ++rr)
      atomicAdd(&kvmT[(size_t)(bh * 64 + dt * 16 + li) * 64 + w * 16 + kq * 4 + rr],
                acc[dt][rr]);
  #pragma unroll
  for (int j = 0; j < 8; ++j) {
    float s = ks[j];
    s += __shfl_xor(s, 8);
    s += __shfl_xor(s, 16);
    s += __shfl_xor(s, 32);
    if ((lane & 56) == 0) atomicAdd(&ksum[bh * 64 + cg + j], s);
  }
}

// ---------------- attnout via MFMA: out[n][d] = z(n) * sum_c q[n][c]*kvm[c][d] ----------------
__global__ __launch_bounds__(256, 3) void attnout_kernel(
    const ushort* __restrict__ qf, const float* __restrict__ kvmT,
    const float* __restrict__ ksum, ushort* __restrict__ out)
{
  __shared__ ushort As[8 * 256 * 8];  // [kb][row][8] bf16 = 32KB
  __shared__ ushort Bs[8 * 64 * 8];   // [kb][d][8] bf16 = 8KB
  __shared__ float zrow[256];
  __shared__ float ksl[64];
  const int bh = blockIdx.x, bb = bh >> 3, h = bh & 7;
  const int n0 = blockIdx.y * 256;
  const int tid = threadIdx.x;
  const int lane = tid & 63;
  const int li   = lane & 15;
  const int kq   = lane >> 4;
  const int wv   = tid >> 6;
  const int w64  = tid & 192;

  #pragma unroll
  for (int it = 0; it < 8; ++it) {
    const int c   = it * 256 + tid;
    const int cw  = it * 256 + w64;
    const int kb  = c >> 8;
    const int row = c & 255;
    GLOAD16(qf + ((size_t)(bb * N_ + n0 + row)) * 512 + h * 64 + kb * 8,
            &As[cw * 8]);
  }
  {
    const int d  = tid >> 2;
    const int cg = (tid & 3) * 16;
    const float* src = &kvmT[(size_t)(bh * 64 + d) * 64 + cg];
    const float4 f0 = *(const float4*)&src[0];
    const float4 f1 = *(const float4*)&src[4];
    const float4 f2 = *(const float4*)&src[8];
    const float4 f3 = *(const float4*)&src[12];
    u16x8 b0, b1;
    b0[0]=f2bf(f0.x); b0[1]=f2bf(f0.y); b0[2]=f2bf(f0.z); b0[3]=f2bf(f0.w);
    b0[4]=f2bf(f1.x); b0[5]=f2bf(f1.y); b0[6]=f2bf(f1.z); b0[7]=f2bf(f1.w);
    b1[0]=f2bf(f2.x); b1[1]=f2bf(f2.y); b1[2]=f2bf(f2.z); b1[3]=f2bf(f2.w);
    b1[4]=f2bf(f3.x); b1[5]=f2bf(f3.y); b1[6]=f2bf(f3.z); b1[7]=f2bf(f3.w);
    *(u16x8*)&Bs[(((cg >> 3)    ) * 64 + d) * 8] = b0;
    *(u16x8*)&Bs[(((cg >> 3) + 1) * 64 + d) * 8] = b1;
  }
  if (tid < 64) ksl[tid] = ksum[bh * 64 + tid];
  __syncthreads();

  {
    float p = 0.f;
    #pragma unroll
    for (int kb = 0; kb < 8; ++kb) {
      const u16x8 qv = *(const u16x8*)&As[(kb * 256 + tid) * 8];
      #pragma unroll
      for (int j = 0; j < 8; ++j) p = fmaf(bf2f(qv[j]), ksl[kb * 8 + j], p);
    }
    zrow[tid] = 1.f / (p + 1e-6f);
  }

  f32x4 acc2[4][4] = {};
  #pragma unroll
  for (int kh = 0; kh < 2; ++kh) {
    bf16x8 bv[4];
    #pragma unroll
    for (int dt = 0; dt < 4; ++dt)
      bv[dt] = *(const bf16x8*)&Bs[((kh * 4 + kq) * 64 + dt * 16 + li) * 8];
    #pragma unroll
    for (int mt = 0; mt < 4; ++mt) {
      const bf16x8 av = *(const bf16x8*)&As[((kh * 4 + kq) * 256 + wv * 64 + mt * 16 + li) * 8];
      #pragma unroll
      for (int dt = 0; dt < 4; ++dt)
        acc2[mt][dt] = __builtin_amdgcn_mfma_f32_16x16x32_bf16(av, bv[dt], acc2[mt][dt], 0, 0, 0);
    }
  }
  __syncthreads();

  #pragma unroll
  for (int mt = 0; mt < 4; ++mt) {
    const float4 zv = *(const float4*)&zrow[wv * 64 + mt * 16 + kq * 4];
    const float za[4] = {zv.x, zv.y, zv.z, zv.w};
    const int rowb = n0 + wv * 64 + mt * 16 + kq * 4;
    #pragma unroll
    for (int dt = 0; dt < 4; ++dt) {
      const int col = h * 64 + dt * 16 + li;
      #pragma unroll
      for (int r = 0; r < 4; ++r)
        out[((size_t)(bb * N_ + rowb + r)) * 512 + col] = f2bf(acc2[mt][dt][r] * za[r]);
    }
  }
}

// ---------------- depthwise 5x5 conv (bf16 in/out), register-rolling; += ano; emits proj input ----------------
__global__ __launch_bounds__(256) void dwconv_hi(
    const ushort* __restrict__ qf, const float* __restrict__ w,
    const float* __restrict__ wb, const ushort* __restrict__ ano,
    ushort* __restrict__ oh)
{
  __shared__ float ws_[64 * 25];
  const int tid = threadIdx.x;
  for (int i = tid; i < 64 * 25; i += 256) ws_[i] = w[i];
  __syncthreads();

  const int bh = blockIdx.x, bb = bh >> 3, h = bh & 7;
  const int hd = tid & 63;
  const int s  = blockIdx.y * 4 + (tid >> 6);
  const int x  = s & 63;
  const int y0 = (s >> 6) * 8;

  float wreg[25];
  #pragma unroll
  for (int i = 0; i < 25; ++i) wreg[i] = ws_[hd * 25 + i];

  float acc[8];
  const float bias = wb[hd];
  #pragma unroll
  for (int j = 0; j < 8; ++j) acc[j] = bias;

  const ushort* base = qf + (size_t)bb * N_ * 512 + h * 64 + hd;
  #pragma unroll
  for (int kx = 0; kx < 5; ++kx) {
    const int xx  = x + kx - 2;
    const bool xok = (unsigned)xx < 64u;
    const int xxc = min(max(xx, 0), 63);
    float col[12];
    #pragma unroll
    for (int r = 0; r < 12; ++r) {
      const int yy  = y0 + r - 2;
      const bool ok = xok && ((unsigned)yy < 64u);
      const int yyc = min(max(yy, 0), 63);
      const float v = bf2f(base[(size_t)(yyc * 64 + xxc) * 512]);
      col[r] = ok ? v : 0.f;
    }
    #pragma unroll
    for (int ky = 0; ky < 5; ++ky) {
      const float wv = wreg[ky * 5 + kx];
      #pragma unroll
      for (int j = 0; j < 8; ++j)
        acc[j] = fmaf(wv, col[j + ky], acc[j]);
    }
  }

  #pragma unroll
  for (int j = 0; j < 8; ++j) {
    const int p = (y0 + j) * 64 + x;
    const size_t idx = ((size_t)(bb * N_ + p)) * 512 + h * 64 + hd;
    oh[idx] = f2bf(bf2f(ano[idx]) + acc[j]);
  }
}

extern "C" void kernel_launch(void* const* d_in, const int* in_sizes, int n_in,
                              void* d_out, int out_size, void* d_ws, size_t ws_size,
                              hipStream_t stream) {
  (void)in_sizes; (void)n_in; (void)out_size; (void)ws_size;
  const float* x     = (const float*)d_in[0];
  const float* Wq    = (const float*)d_in[1];
  const float* Wkv   = (const float*)d_in[2];
  const float* Wp    = (const float*)d_in[3];
  const float* bp    = (const float*)d_in[4];
  const float* sp    = (const float*)d_in[5];
  const float* dwc_w = (const float*)d_in[6];
  const float* dwc_b = (const float*)d_in[7];
  float* out = (float*)d_out;

  char* ws = (char*)d_ws;
  ushort* xh   = (ushort*)ws;                        // 32MB: x hi; later proj-input (bf16)
  ushort* qbuf = (ushort*)(ws + 33554432ull);        // 32MB focused q (bf16)
  ushort* kbuf = (ushort*)(ws + 67108864ull);        // 32MB k (bf16); later ano (bf16)
  char*   w0   = ws + 100663296ull;
  ushort* Bqh  = (ushort*)w0;                        // 1536x512 bf16 (rows: Wq 0..511, Wkv 512..1535)
  ushort* Bph  = Bqh + 786432;                       // 512x512 bf16
  float*  kvmb = (float*)(Bph + 262144);             // 1MB (kvmT)
  float*  ksum = kvmb + 262144;                      // 16KB
  float*  sinv = ksum + 4096;                        // 2KB
  ushort* vbuf = (ushort*)d_out;                     // v (bf16, 32MB) aliases d_out
  ushort* ano  = kbuf;                               // attn-out aliases k

  const int M = B_ * N_;  // 32768

  scale_kernel<<<1, 512, 0, stream>>>(sp, sinv);
  cvt_hi<<<8192, 256, 0, stream>>>(x, xh);
  cvt_w_t<<<128, 256, 0, stream>>>(Wq, Bqh, 512);
  // Wkv occupies rows [512,1536): offset = 512 rows * 512 stride = 262144
  cvt_w_t<<<256, 256, 0, stream>>>(Wkv, Bqh + 262144, 1024);
  cvt_w_t<<<128, 256, 0, stream>>>(Wp, Bph, 512);
  // fused q|k|v GEMM (256^2 tiles): 128 row-blocks x 6 col-blocks = 768 blocks
  gemm_bf16<<<768, 512, 0, stream>>>(
      xh, Bqh, nullptr, qbuf, kbuf, vbuf, nullptr, 6, 512, 1024, 1, 1, 0);
  focus2<<<2 * M / 4, 256, 0, stream>>>(qbuf, kbuf, sinv);
  hipMemsetAsync(kvmb, 0, (262144 + 4096) * sizeof(float), stream);
  // kvm via MFMA: grid (bh, 8 n-splits of 512)
  kvm_kernel<<<dim3(BH_, 8), 256, 0, stream>>>(kbuf, vbuf, kvmb, ksum);
  attnout_kernel<<<dim3(BH_, N_ / 256), 256, 0, stream>>>(qbuf, kvmb, ksum, ano);
  dwconv_hi<<<dim3(BH_, 128), 256, 0, stream>>>(qbuf, dwc_w, dwc_b, ano, xh);
  // proj (256^2 tiles): 128 x 2 = 256 blocks; fp32 out + bias -> d_out
  gemm_bf16<<<256, 512, 0, stream>>>(
      xh, Bph, bp, nullptr, nullptr, nullptr, out, 2, 512, 512, 0, 0, 0);
}